// Round 1
// baseline (633.570 us; speedup 1.0000x reference)
//
#include <hip/hip_runtime.h>
#include <hip/hip_bf16.h>

typedef __bf16 bf16x8 __attribute__((ext_vector_type(8)));
typedef float  f32x4  __attribute__((ext_vector_type(4)));

#define SEQ   1024
#define BATCH 8
#define DIMM  512
#define HEADS 8
#define DHEAD 64
#define TRIPLE 1536
#define MROWS (BATCH*SEQ)   // 8192

// ---------------- scale reduction (deterministic two-stage) ----------------
__global__ void absum_partial(const float* __restrict__ w, int n, float* __restrict__ part) {
    __shared__ float red[4];
    float s = 0.f;
    for (int i = blockIdx.x * blockDim.x + threadIdx.x; i < n; i += gridDim.x * blockDim.x)
        s += fabsf(w[i]);
    for (int o = 32; o; o >>= 1) s += __shfl_down(s, o);
    int lane = threadIdx.x & 63, wv = threadIdx.x >> 6;
    if (!lane) red[wv] = s;
    __syncthreads();
    if (threadIdx.x == 0) {
        float t = red[0] + red[1] + red[2] + red[3];
        part[blockIdx.x] = t;
    }
}

__global__ void finalize_scales(const float* __restrict__ p1, const float* __restrict__ p2,
                                float* __restrict__ scales) {
    if (threadIdx.x == 0) {
        float s1 = 0.f, s2 = 0.f;
        for (int i = 0; i < 256; ++i) s1 += p1[i];
        for (int i = 0; i < 256; ++i) s2 += p2[i];
        scales[0] = s1 / 786432.0f;   // 1536*512
        scales[1] = s2 / 262144.0f;   // 512*512
    }
}

// ---------------- ternary quantize -> bf16 ----------------
__global__ void quant_ternary(const float* __restrict__ w, int n,
                              const float* __restrict__ scp, int si,
                              __bf16* __restrict__ out) {
    float s = scp[si];
    float inv = 1.f / (s + 1e-6f);
    int idx = (blockIdx.x * blockDim.x + threadIdx.x) * 4;
    if (idx + 3 < n) {
        float4 v = *reinterpret_cast<const float4*>(w + idx);
        out[idx + 0] = (__bf16)(rintf(fminf(1.f, fmaxf(-1.f, v.x * inv))) * s);
        out[idx + 1] = (__bf16)(rintf(fminf(1.f, fmaxf(-1.f, v.y * inv))) * s);
        out[idx + 2] = (__bf16)(rintf(fminf(1.f, fmaxf(-1.f, v.z * inv))) * s);
        out[idx + 3] = (__bf16)(rintf(fminf(1.f, fmaxf(-1.f, v.w * inv))) * s);
    }
}

// ---------------- layernorm (row = 512), output bf16 ----------------
template<typename TIN>
__global__ __launch_bounds__(256) void ln_rows(const TIN* __restrict__ x,
                                               const float* __restrict__ g,
                                               const float* __restrict__ bta,
                                               __bf16* __restrict__ y) {
    int row = blockIdx.x;
    int t = threadIdx.x;
    const TIN* xr = x + (size_t)row * DIMM;
    float v0 = (float)xr[t * 2], v1 = (float)xr[t * 2 + 1];
    float s = v0 + v1, sq = v0 * v0 + v1 * v1;
    for (int o = 32; o; o >>= 1) { s += __shfl_down(s, o); sq += __shfl_down(sq, o); }
    __shared__ float rs[4], rq[4], mb[2];
    int lane = t & 63, wv = t >> 6;
    if (!lane) { rs[wv] = s; rq[wv] = sq; }
    __syncthreads();
    if (t == 0) {
        float S = rs[0] + rs[1] + rs[2] + rs[3];
        float Q = rq[0] + rq[1] + rq[2] + rq[3];
        float mu = S * (1.f / DIMM);
        float var = Q * (1.f / DIMM) - mu * mu;
        mb[0] = mu; mb[1] = rsqrtf(var + 1e-5f);
    }
    __syncthreads();
    float mu = mb[0], invs = mb[1];
    y[(size_t)row * DIMM + t * 2]     = (__bf16)((v0 - mu) * invs * g[t * 2]     + bta[t * 2]);
    y[(size_t)row * DIMM + t * 2 + 1] = (__bf16)((v1 - mu) * invs * g[t * 2 + 1] + bta[t * 2 + 1]);
}

// ---------------- MFMA GEMM: C[M,N] = A[M,512] @ Wt[N,512]^T (+bias) ----------------
// per-wave 64x64 tile, direct-from-global fragments (L2-resident operands).
template<int NCOLS, bool BIAS, bool OUT_F32>
__global__ __launch_bounds__(256) void gemm_bf16(const __bf16* __restrict__ A,
                                                 const __bf16* __restrict__ Wt,
                                                 const float* __restrict__ bias,
                                                 __bf16* __restrict__ outb,
                                                 float* __restrict__ outf) {
    const int K = DIMM;
    int w = threadIdx.x >> 6, lane = threadIdx.x & 63;
    int m0 = blockIdx.x * 128 + (w >> 1) * 64;
    int n0 = blockIdx.y * 128 + (w & 1) * 64;
    int lr = lane & 15;
    int lk = (lane >> 4) * 8;
    f32x4 acc[4][4] = {};
    const __bf16* Ap = A  + (size_t)(m0 + lr) * K + lk;
    const __bf16* Bp = Wt + (size_t)(n0 + lr) * K + lk;
    for (int k0 = 0; k0 < K; k0 += 32) {
        bf16x8 af[4], bfr[4];
#pragma unroll
        for (int i = 0; i < 4; ++i) af[i]  = *reinterpret_cast<const bf16x8*>(Ap + (size_t)i * 16 * K + k0);
#pragma unroll
        for (int i = 0; i < 4; ++i) bfr[i] = *reinterpret_cast<const bf16x8*>(Bp + (size_t)i * 16 * K + k0);
#pragma unroll
        for (int i = 0; i < 4; ++i)
#pragma unroll
            for (int j = 0; j < 4; ++j)
                acc[i][j] = __builtin_amdgcn_mfma_f32_16x16x32_bf16(af[i], bfr[j], acc[i][j], 0, 0, 0);
    }
    int orow0 = m0 + (lane >> 4) * 4;
#pragma unroll
    for (int i = 0; i < 4; ++i)
#pragma unroll
        for (int j = 0; j < 4; ++j)
#pragma unroll
            for (int r = 0; r < 4; ++r) {
                int row = orow0 + i * 16 + r;
                int col = n0 + j * 16 + lr;
                float v = acc[i][j][r];
                if (BIAS) v += bias[col];
                if (OUT_F32) outf[(size_t)row * NCOLS + col] = v;
                else         outb[(size_t)row * NCOLS + col] = (__bf16)v;
            }
}

// ---------------- fp32 flash attention ----------------
// grid: (64 q-tiles of 16 rows, 64 b*h). block 256 = 4 waves, 4 q-rows/wave.
__global__ __launch_bounds__(256) void attn_fp32(const __bf16* __restrict__ qkv,
                                                 __bf16* __restrict__ out) {
    int qt = blockIdx.x;
    int bh = blockIdx.y;
    int b = bh >> 3, h = bh & 7;
    int tid = threadIdx.x, w = tid >> 6, lane = tid & 63;

    __shared__ __bf16 Kl[64 * 64];
    __shared__ __bf16 Vl[64 * 64];
    __shared__ float  ql[16][64];
    __shared__ float  pl[4][4][64];

    // stage q (pre-scaled by 1/8)
    {
        int r = tid >> 4;
        int d0 = (tid & 15) * 4;
        const __bf16* src = qkv + (size_t)(b * SEQ + qt * 16 + r) * TRIPLE + h * DHEAD + d0;
        for (int e = 0; e < 4; ++e) ql[r][d0 + e] = (float)src[e] * 0.125f;
    }

    float mrun[4], lrun[4], oacc[4], alph[4];
#pragma unroll
    for (int i = 0; i < 4; ++i) { mrun[i] = -1e30f; lrun[i] = 0.f; oacc[i] = 0.f; }

    uint4* kd = reinterpret_cast<uint4*>(Kl);
    uint4* vd = reinterpret_cast<uint4*>(Vl);
    const __bf16* vl16 = Vl;

    for (int t = 0; t < 16; ++t) {
        __syncthreads();  // previous tile fully consumed
        {
            int r = tid >> 2;             // key row 0..63
            int c0 = (tid & 3) * 2;       // 16B-chunk pair
            const uint4* Ks = reinterpret_cast<const uint4*>(qkv + (size_t)(b * SEQ + t * 64 + r) * TRIPLE + DIMM + h * DHEAD);
            const uint4* Vs = reinterpret_cast<const uint4*>(qkv + (size_t)(b * SEQ + t * 64 + r) * TRIPLE + 2 * DIMM + h * DHEAD);
            int sw = r & 7;
            kd[r * 8 + (c0 ^ sw)]       = Ks[c0];
            kd[r * 8 + ((c0 + 1) ^ sw)] = Ks[c0 + 1];
            vd[r * 8 + (c0 ^ sw)]       = Vs[c0];
            vd[r * 8 + ((c0 + 1) ^ sw)] = Vs[c0 + 1];
        }
        __syncthreads();

        // ---- phase A: lane = key j ----
        int j = lane;
        int swj = j & 7;
        float sc[4] = {0.f, 0.f, 0.f, 0.f};
#pragma unroll
        for (int c = 0; c < 8; ++c) {
            bf16x8 kv = *reinterpret_cast<const bf16x8*>(&kd[j * 8 + (c ^ swj)]);
            float kf[8];
#pragma unroll
            for (int e = 0; e < 8; ++e) kf[e] = (float)kv[e];
#pragma unroll
            for (int i = 0; i < 4; ++i) {
                const float* qp = &ql[w * 4 + i][c * 8];
                float4 qa = *reinterpret_cast<const float4*>(qp);
                float4 qb = *reinterpret_cast<const float4*>(qp + 4);
                sc[i] += kf[0] * qa.x + kf[1] * qa.y + kf[2] * qa.z + kf[3] * qa.w
                       + kf[4] * qb.x + kf[5] * qb.y + kf[6] * qb.z + kf[7] * qb.w;
            }
        }
#pragma unroll
        for (int i = 0; i < 4; ++i) {
            float mx = sc[i];
            for (int o = 32; o; o >>= 1) mx = fmaxf(mx, __shfl_xor(mx, o));
            float mnew = fmaxf(mrun[i], mx);
            float p = __expf(sc[i] - mnew);
            float ps = p;
            for (int o = 32; o; o >>= 1) ps += __shfl_xor(ps, o);
            alph[i] = __expf(mrun[i] - mnew);
            lrun[i] = lrun[i] * alph[i] + ps;
            mrun[i] = mnew;
            pl[w][i][j] = p;
        }

        // ---- phase B: lane = dim d (same-wave LDS; DS ops are in-order per wave) ----
        int d = lane;
        int dc = d >> 3, db = d & 7;
#pragma unroll
        for (int i = 0; i < 4; ++i) oacc[i] *= alph[i];
        for (int jj = 0; jj < 64; ++jj) {
            float vv = (float)vl16[(jj * 8 + (dc ^ (jj & 7))) * 8 + db];
            float4 pv = make_float4(pl[w][0][jj], pl[w][1][jj], pl[w][2][jj], pl[w][3][jj]);
            oacc[0] += pv.x * vv;
            oacc[1] += pv.y * vv;
            oacc[2] += pv.z * vv;
            oacc[3] += pv.w * vv;
        }
    }

#pragma unroll
    for (int i = 0; i < 4; ++i) {
        float o = oacc[i] / lrun[i];
        int row = b * SEQ + qt * 16 + w * 4 + i;
        out[(size_t)row * DIMM + h * DHEAD + lane] = (__bf16)o;
    }
}

// ---------------- launch ----------------
extern "C" void kernel_launch(void* const* d_in, const int* in_sizes, int n_in,
                              void* d_out, int out_size, void* d_ws, size_t ws_size,
                              hipStream_t stream) {
    const float* x     = (const float*)d_in[0];
    const float* g1    = (const float*)d_in[1];
    const float* b1    = (const float*)d_in[2];
    const float* W_qkv = (const float*)d_in[3];
    const float* g2    = (const float*)d_in[4];
    const float* b2    = (const float*)d_in[5];
    const float* W_out = (const float*)d_in[6];
    const float* b_out = (const float*)d_in[7];
    float* out = (float*)d_out;

    char* ws = (char*)d_ws;
    float* part1  = (float*)(ws);
    float* part2  = (float*)(ws + 1024);
    float* scales = (float*)(ws + 2048);
    __bf16* Wq1 = (__bf16*)(ws + 4096);                          // [1536,512]
    __bf16* Wq2 = (__bf16*)(ws + 4096 + 1572864);                // [512,512]
    __bf16* Xln = (__bf16*)(ws + 4096 + 1572864 + 524288);       // [8192,512] (reused for LN2 out)
    __bf16* QKV = (__bf16*)(ws + 4096 + 1572864 + 524288 + 8388608);            // [8192,1536]
    __bf16* AO  = (__bf16*)(ws + 4096 + 1572864 + 524288 + 8388608 + 25165824); // [8192,512]

    absum_partial<<<256, 256, 0, stream>>>(W_qkv, 786432, part1);
    absum_partial<<<256, 256, 0, stream>>>(W_out, 262144, part2);
    finalize_scales<<<1, 64, 0, stream>>>(part1, part2, scales);
    quant_ternary<<<768, 256, 0, stream>>>(W_qkv, 786432, scales, 0, Wq1);
    quant_ternary<<<256, 256, 0, stream>>>(W_out, 262144, scales, 1, Wq2);
    ln_rows<float><<<MROWS, 256, 0, stream>>>(x, g1, b1, Xln);
    gemm_bf16<TRIPLE, false, false><<<dim3(64, 12), 256, 0, stream>>>(Xln, Wq1, nullptr, QKV, nullptr);
    attn_fp32<<<dim3(64, 64), 256, 0, stream>>>(QKV, AO);
    ln_rows<__bf16><<<MROWS, 256, 0, stream>>>(AO, g2, b2, Xln);
    gemm_bf16<DIMM, true, true><<<dim3(64, 4), 256, 0, stream>>>(Xln, Wq2, b_out, nullptr, out);
}

// Round 3
// 146.963 us; speedup vs baseline: 4.3111x; 4.3111x over previous
//
#include <hip/hip_runtime.h>
#include <hip/hip_bf16.h>

typedef __bf16 bf16x8 __attribute__((ext_vector_type(8)));
typedef float  f32x4  __attribute__((ext_vector_type(4)));

#define SEQ   1024
#define BATCH 8
#define DIMM  512
#define HEADS 8
#define DHEAD 64
#define TRIPLE 1536
#define MROWS (BATCH*SEQ)   // 8192

// ---------------- scale reduction (deterministic two-stage) ----------------
__global__ void absum_partial(const float* __restrict__ w, int n, float* __restrict__ part) {
    __shared__ float red[4];
    float s = 0.f;
    for (int i = blockIdx.x * blockDim.x + threadIdx.x; i < n; i += gridDim.x * blockDim.x)
        s += fabsf(w[i]);
    for (int o = 32; o; o >>= 1) s += __shfl_down(s, o);
    int lane = threadIdx.x & 63, wv = threadIdx.x >> 6;
    if (!lane) red[wv] = s;
    __syncthreads();
    if (threadIdx.x == 0) {
        float t = red[0] + red[1] + red[2] + red[3];
        part[blockIdx.x] = t;
    }
}

__global__ void finalize_scales(const float* __restrict__ p1, const float* __restrict__ p2,
                                float* __restrict__ scales) {
    if (threadIdx.x == 0) {
        float s1 = 0.f, s2 = 0.f;
        for (int i = 0; i < 256; ++i) s1 += p1[i];
        for (int i = 0; i < 256; ++i) s2 += p2[i];
        scales[0] = s1 / 786432.0f;   // 1536*512
        scales[1] = s2 / 262144.0f;   // 512*512
    }
}

// ---------------- ternary quantize -> bf16 ----------------
__global__ void quant_ternary(const float* __restrict__ w, int n,
                              const float* __restrict__ scp, int si,
                              __bf16* __restrict__ out) {
    float s = scp[si];
    float inv = 1.f / (s + 1e-6f);
    int idx = (blockIdx.x * blockDim.x + threadIdx.x) * 4;
    if (idx + 3 < n) {
        float4 v = *reinterpret_cast<const float4*>(w + idx);
        out[idx + 0] = (__bf16)(rintf(fminf(1.f, fmaxf(-1.f, v.x * inv))) * s);
        out[idx + 1] = (__bf16)(rintf(fminf(1.f, fmaxf(-1.f, v.y * inv))) * s);
        out[idx + 2] = (__bf16)(rintf(fminf(1.f, fmaxf(-1.f, v.z * inv))) * s);
        out[idx + 3] = (__bf16)(rintf(fminf(1.f, fmaxf(-1.f, v.w * inv))) * s);
    }
}

// ---------------- layernorm (row = 512), output bf16 ----------------
template<typename TIN>
__global__ __launch_bounds__(256) void ln_rows(const TIN* __restrict__ x,
                                               const float* __restrict__ g,
                                               const float* __restrict__ bta,
                                               __bf16* __restrict__ y) {
    int row = blockIdx.x;
    int t = threadIdx.x;
    const TIN* xr = x + (size_t)row * DIMM;
    float v0 = (float)xr[t * 2], v1 = (float)xr[t * 2 + 1];
    float s = v0 + v1, sq = v0 * v0 + v1 * v1;
    for (int o = 32; o; o >>= 1) { s += __shfl_down(s, o); sq += __shfl_down(sq, o); }
    __shared__ float rs[4], rq[4], mb[2];
    int lane = t & 63, wv = t >> 6;
    if (!lane) { rs[wv] = s; rq[wv] = sq; }
    __syncthreads();
    if (t == 0) {
        float S = rs[0] + rs[1] + rs[2] + rs[3];
        float Q = rq[0] + rq[1] + rq[2] + rq[3];
        float mu = S * (1.f / DIMM);
        float var = Q * (1.f / DIMM) - mu * mu;
        mb[0] = mu; mb[1] = rsqrtf(var + 1e-5f);
    }
    __syncthreads();
    float mu = mb[0], invs = mb[1];
    y[(size_t)row * DIMM + t * 2]     = (__bf16)((v0 - mu) * invs * g[t * 2]     + bta[t * 2]);
    y[(size_t)row * DIMM + t * 2 + 1] = (__bf16)((v1 - mu) * invs * g[t * 2 + 1] + bta[t * 2 + 1]);
}

// ---------------- MFMA GEMM: C[M,N] = A[M,512] @ Wt[N,512]^T (+bias) ----------------
template<int NCOLS, bool BIAS, bool OUT_F32>
__global__ __launch_bounds__(256) void gemm_bf16(const __bf16* __restrict__ A,
                                                 const __bf16* __restrict__ Wt,
                                                 const float* __restrict__ bias,
                                                 __bf16* __restrict__ outb,
                                                 float* __restrict__ outf) {
    const int K = DIMM;
    int w = threadIdx.x >> 6, lane = threadIdx.x & 63;
    int m0 = blockIdx.x * 128 + (w >> 1) * 64;
    int n0 = blockIdx.y * 128 + (w & 1) * 64;
    int lr = lane & 15;
    int lk = (lane >> 4) * 8;
    f32x4 acc[4][4] = {};
    const __bf16* Ap = A  + (size_t)(m0 + lr) * K + lk;
    const __bf16* Bp = Wt + (size_t)(n0 + lr) * K + lk;
    for (int k0 = 0; k0 < K; k0 += 32) {
        bf16x8 af[4], bfr[4];
#pragma unroll
        for (int i = 0; i < 4; ++i) af[i]  = *reinterpret_cast<const bf16x8*>(Ap + (size_t)i * 16 * K + k0);
#pragma unroll
        for (int i = 0; i < 4; ++i) bfr[i] = *reinterpret_cast<const bf16x8*>(Bp + (size_t)i * 16 * K + k0);
#pragma unroll
        for (int i = 0; i < 4; ++i)
#pragma unroll
            for (int j = 0; j < 4; ++j)
                acc[i][j] = __builtin_amdgcn_mfma_f32_16x16x32_bf16(af[i], bfr[j], acc[i][j], 0, 0, 0);
    }
    int orow0 = m0 + (lane >> 4) * 4;
#pragma unroll
    for (int i = 0; i < 4; ++i)
#pragma unroll
        for (int j = 0; j < 4; ++j)
#pragma unroll
            for (int r = 0; r < 4; ++r) {
                int row = orow0 + i * 16 + r;
                int col = n0 + j * 16 + lr;
                float v = acc[i][j][r];
                if (BIAS) v += bias[col];
                if (OUT_F32) outf[(size_t)row * NCOLS + col] = v;
                else         outb[(size_t)row * NCOLS + col] = (__bf16)v;
            }
}

// ---------------- MFMA flash attention (compiler-fenced, reg-staged) ----------------
// grid (8 q-blocks of 128 rows, 64 b*h); 512 threads = 8 waves, 16 q-rows/wave.
// S^T = mfma(K_frag, Q_frag)  -> lane owns q-row (lane&15): softmax lane-local + 2 shfl.
// P -> per-wave LDS (bf16) -> O^T = mfma(Vt_frag, P_frag): rescale + 1/l lane-local.
// All sync via __syncthreads(); K/V staged global->reg->ds_write with both-side swizzles.
__global__ __launch_bounds__(512, 4) void attn_mfma(const __bf16* __restrict__ qkv,
                                                    __bf16* __restrict__ out) {
    const int qt = blockIdx.x, bh = blockIdx.y;
    const int b = bh >> 3, h = bh & 7;
    const int tid = threadIdx.x;
    const int w = tid >> 6, lane = tid & 63;
    const int g = lane >> 4, m = lane & 15;

    __shared__ __align__(16) __bf16 Kb[4096];      // [64 key][64 d], 128B rows, chunk c at c^(key&7)
    __shared__ __align__(16) __bf16 Vt[4096];      // [64 d][64 key], 128B rows, chunk c at c^((d>>3)^(d&7))
    __shared__ __align__(16) __bf16 Pl[8][1024];   // per-wave [16 q][64 key], chunk c at c^(q&7)

    // Q fragments (B-frag: lane holds Q[q=m][kc*32 + g*8 + j]); *0.125 exact in bf16
    bf16x8 qf[2];
    {
        const __bf16* qp = qkv + (size_t)(b * SEQ + qt * 128 + w * 16 + m) * TRIPLE + h * 64 + g * 8;
        qf[0] = *reinterpret_cast<const bf16x8*>(qp);
        qf[1] = *reinterpret_cast<const bf16x8*>(qp + 32);
#pragma unroll
        for (int e = 0; e < 8; ++e) {
            qf[0][e] = (__bf16)((float)qf[0][e] * 0.125f);
            qf[1][e] = (__bf16)((float)qf[1][e] * 0.125f);
        }
    }

    // staging addresses: thread -> key row (tid>>3), d-chunk (tid&7)
    const int krow = tid >> 3;          // 0..63
    const int dc   = tid & 7;           // 0..7
    const size_t rbase = (size_t)(b * SEQ + krow) * TRIPLE + h * 64 + dc * 8;
    const __bf16* ksrc = qkv + rbase + DIMM;
    const __bf16* vsrc = qkv + rbase + 2 * DIMM;
    const int kstep = 64 * TRIPLE;

    char* kwp = (char*)Kb + krow * 128 + ((dc ^ (krow & 7)) << 4);
    char* vwp = (char*)Vt + dc * 1024 + (krow * 2);

    f32x4 oa[4] = {};
    float mrun = -1e30f, lrun = 0.f;

    uint4 kr_cur = *reinterpret_cast<const uint4*>(ksrc);
    uint4 vr_cur = *reinterpret_cast<const uint4*>(vsrc);
    uint4 kr_nxt = {}, vr_nxt = {};

    for (int t = 0; t < 16; ++t) {
        __syncthreads();   // all waves done reading tile t-1 LDS; tile-t loads landed (vmcnt drain)

        // stage K (one b128, swizzled) and V (transpose scatter, per-e swizzle)
        *reinterpret_cast<bf16x8*>(kwp) = *reinterpret_cast<bf16x8*>(&kr_cur);
        {
            bf16x8 vv = *reinterpret_cast<bf16x8*>(&vr_cur);
#pragma unroll
            for (int e = 0; e < 8; ++e)
                *(__bf16*)(vwp + e * 128 + (((krow * 2) ^ (((dc ^ e) & 7) << 4)) - krow * 2)) = vv[e];
        }
        __syncthreads();   // tile t visible (lgkm drained)

        if (t < 15) {      // issue t+1 loads; overlap with compute below
            kr_nxt = *reinterpret_cast<const uint4*>(ksrc + (size_t)(t + 1) * kstep);
            vr_nxt = *reinterpret_cast<const uint4*>(vsrc + (size_t)(t + 1) * kstep);
        }

        // ---- S^T = K @ Q^T ----
        const char* kb = (const char*)Kb;
        f32x4 sa[4];
#pragma unroll
        for (int i = 0; i < 4; ++i) sa[i] = (f32x4){0.f, 0.f, 0.f, 0.f};
#pragma unroll
        for (int kc = 0; kc < 2; ++kc) {
            const int cp = ((kc * 4 + g) ^ (m & 7)) << 4;
#pragma unroll
            for (int i = 0; i < 4; ++i) {
                bf16x8 kf = *reinterpret_cast<const bf16x8*>(kb + (i * 16 + m) * 128 + cp);
                sa[i] = __builtin_amdgcn_mfma_f32_16x16x32_bf16(kf, qf[kc], sa[i], 0, 0, 0);
            }
        }

        // ---- online softmax (lane owns q=m; keys i*16+g*4+r in-lane) ----
        float mx = -1e30f;
#pragma unroll
        for (int i = 0; i < 4; ++i)
#pragma unroll
            for (int r = 0; r < 4; ++r) mx = fmaxf(mx, sa[i][r]);
        mx = fmaxf(mx, __shfl_xor(mx, 16));
        mx = fmaxf(mx, __shfl_xor(mx, 32));
        const float mnew = fmaxf(mrun, mx);
        float p[4][4];
        float ps = 0.f;
#pragma unroll
        for (int i = 0; i < 4; ++i)
#pragma unroll
            for (int r = 0; r < 4; ++r) { p[i][r] = __expf(sa[i][r] - mnew); ps += p[i][r]; }
        ps += __shfl_xor(ps, 16);
        ps += __shfl_xor(ps, 32);
        const float al = __expf(mrun - mnew);
        mrun = mnew;
        lrun = lrun * al + ps;
#pragma unroll
        for (int i = 0; i < 4; ++i)
#pragma unroll
            for (int r = 0; r < 4; ++r) oa[i][r] *= al;

        // ---- P -> per-wave LDS (bf16 packed, b64 stores) ----
        char* pw = (char*)Pl[w] + m * 128;
        const int psw = (m & 7) << 4;
#pragma unroll
        for (int i = 0; i < 4; ++i) {
            uint2 pk;
            asm("v_cvt_pk_bf16_f32 %0, %1, %2" : "=v"(pk.x) : "v"(p[i][0]), "v"(p[i][1]));
            asm("v_cvt_pk_bf16_f32 %0, %1, %2" : "=v"(pk.y) : "v"(p[i][2]), "v"(p[i][3]));
            *reinterpret_cast<uint2*>(pw + ((i * 32 + g * 8) ^ psw)) = pk;
        }

        // ---- O^T += V^T @ P^T ----
        bf16x8 pf[2];
#pragma unroll
        for (int kc = 0; kc < 2; ++kc)
            pf[kc] = *reinterpret_cast<const bf16x8*>(pw + ((kc * 64 + g * 16) ^ psw));
        const char* vb = (const char*)Vt;
#pragma unroll
        for (int kc = 0; kc < 2; ++kc)
#pragma unroll
            for (int i = 0; i < 4; ++i) {
                const int sv = ((i * 2 + (m >> 3)) ^ (m & 7)) & 7;
                bf16x8 vf = *reinterpret_cast<const bf16x8*>(
                    vb + (i * 16 + m) * 128 + (((kc * 4 + g) ^ sv) << 4));
                oa[i] = __builtin_amdgcn_mfma_f32_16x16x32_bf16(vf, pf[kc], oa[i], 0, 0, 0);
            }

        kr_cur = kr_nxt;
        vr_cur = vr_nxt;
    }

    // ---- epilogue: O[q=m][d=i*16+g*4+r] / lrun ----
    const float inv = 1.0f / lrun;
    unsigned int* orow = (unsigned int*)(out + (size_t)(b * SEQ + qt * 128 + w * 16 + m) * DIMM + h * 64);
#pragma unroll
    for (int i = 0; i < 4; ++i)
#pragma unroll
        for (int rp = 0; rp < 2; ++rp) {
            float o0 = oa[i][2 * rp] * inv, o1 = oa[i][2 * rp + 1] * inv;
            unsigned int pk;
            asm("v_cvt_pk_bf16_f32 %0, %1, %2" : "=v"(pk) : "v"(o0), "v"(o1));
            orow[i * 8 + g * 2 + rp] = pk;
        }
}

// ---------------- launch ----------------
extern "C" void kernel_launch(void* const* d_in, const int* in_sizes, int n_in,
                              void* d_out, int out_size, void* d_ws, size_t ws_size,
                              hipStream_t stream) {
    const float* x     = (const float*)d_in[0];
    const float* g1    = (const float*)d_in[1];
    const float* b1    = (const float*)d_in[2];
    const float* W_qkv = (const float*)d_in[3];
    const float* g2    = (const float*)d_in[4];
    const float* b2    = (const float*)d_in[5];
    const float* W_out = (const float*)d_in[6];
    const float* b_out = (const float*)d_in[7];
    float* out = (float*)d_out;

    char* ws = (char*)d_ws;
    float* part1  = (float*)(ws);
    float* part2  = (float*)(ws + 1024);
    float* scales = (float*)(ws + 2048);
    __bf16* Wq1 = (__bf16*)(ws + 4096);                          // [1536,512]
    __bf16* Wq2 = (__bf16*)(ws + 4096 + 1572864);                // [512,512]
    __bf16* Xln = (__bf16*)(ws + 4096 + 1572864 + 524288);       // [8192,512] (reused for LN2 out)
    __bf16* QKV = (__bf16*)(ws + 4096 + 1572864 + 524288 + 8388608);            // [8192,1536]
    __bf16* AO  = (__bf16*)(ws + 4096 + 1572864 + 524288 + 8388608 + 25165824); // [8192,512]

    absum_partial<<<256, 256, 0, stream>>>(W_qkv, 786432, part1);
    absum_partial<<<256, 256, 0, stream>>>(W_out, 262144, part2);
    finalize_scales<<<1, 64, 0, stream>>>(part1, part2, scales);
    quant_ternary<<<768, 256, 0, stream>>>(W_qkv, 786432, scales, 0, Wq1);
    quant_ternary<<<256, 256, 0, stream>>>(W_out, 262144, scales, 1, Wq2);
    ln_rows<float><<<MROWS, 256, 0, stream>>>(x, g1, b1, Xln);
    gemm_bf16<TRIPLE, false, false><<<dim3(64, 12), 256, 0, stream>>>(Xln, Wq1, nullptr, QKV, nullptr);
    attn_mfma<<<dim3(8, 64), 512, 0, stream>>>(QKV, AO);
    ln_rows<__bf16><<<MROWS, 256, 0, stream>>>(AO, g2, b2, Xln);
    gemm_bf16<DIMM, true, true><<<dim3(64, 4), 256, 0, stream>>>(Xln, Wq2, b_out, nullptr, out);
}

// Round 4
// 111.721 us; speedup vs baseline: 5.6710x; 1.3154x over previous
//
#include <hip/hip_runtime.h>
#include <hip/hip_bf16.h>

typedef __bf16 bf16x8 __attribute__((ext_vector_type(8)));
typedef float  f32x4  __attribute__((ext_vector_type(4)));

#define SEQ   1024
#define BATCH 8
#define DIMM  512
#define HEADS 8
#define DHEAD 64
#define TRIPLE 1536
#define MROWS (BATCH*SEQ)   // 8192

#define GLOAD_LDS16(g, l) __builtin_amdgcn_global_load_lds( \
    (const __attribute__((address_space(1))) void*)(const void*)(g), \
    (__attribute__((address_space(3))) void*)(void*)(l), 16, 0, 0)

// ---------------- scale reduction (deterministic two-stage) ----------------
__global__ void absum_partial(const float* __restrict__ w, int n, float* __restrict__ part) {
    __shared__ float red[4];
    float s = 0.f;
    for (int i = blockIdx.x * blockDim.x + threadIdx.x; i < n; i += gridDim.x * blockDim.x)
        s += fabsf(w[i]);
    for (int o = 32; o; o >>= 1) s += __shfl_down(s, o);
    int lane = threadIdx.x & 63, wv = threadIdx.x >> 6;
    if (!lane) red[wv] = s;
    __syncthreads();
    if (threadIdx.x == 0) {
        float t = red[0] + red[1] + red[2] + red[3];
        part[blockIdx.x] = t;
    }
}

__global__ void finalize_scales(const float* __restrict__ p1, const float* __restrict__ p2,
                                float* __restrict__ scales) {
    if (threadIdx.x == 0) {
        float s1 = 0.f, s2 = 0.f;
        for (int i = 0; i < 256; ++i) s1 += p1[i];
        for (int i = 0; i < 256; ++i) s2 += p2[i];
        scales[0] = s1 / 786432.0f;   // 1536*512
        scales[1] = s2 / 262144.0f;   // 512*512
    }
}

// ---------------- ternary quantize -> bf16 ----------------
__global__ void quant_ternary(const float* __restrict__ w, int n,
                              const float* __restrict__ scp, int si,
                              __bf16* __restrict__ out) {
    float s = scp[si];
    float inv = 1.f / (s + 1e-6f);
    int idx = (blockIdx.x * blockDim.x + threadIdx.x) * 4;
    if (idx + 3 < n) {
        float4 v = *reinterpret_cast<const float4*>(w + idx);
        out[idx + 0] = (__bf16)(rintf(fminf(1.f, fmaxf(-1.f, v.x * inv))) * s);
        out[idx + 1] = (__bf16)(rintf(fminf(1.f, fmaxf(-1.f, v.y * inv))) * s);
        out[idx + 2] = (__bf16)(rintf(fminf(1.f, fmaxf(-1.f, v.z * inv))) * s);
        out[idx + 3] = (__bf16)(rintf(fminf(1.f, fmaxf(-1.f, v.w * inv))) * s);
    }
}

// ---------------- layernorm (row = 512), output bf16 ----------------
template<typename TIN>
__global__ __launch_bounds__(256) void ln_rows(const TIN* __restrict__ x,
                                               const float* __restrict__ g,
                                               const float* __restrict__ bta,
                                               __bf16* __restrict__ y) {
    int row = blockIdx.x;
    int t = threadIdx.x;
    const TIN* xr = x + (size_t)row * DIMM;
    float v0 = (float)xr[t * 2], v1 = (float)xr[t * 2 + 1];
    float s = v0 + v1, sq = v0 * v0 + v1 * v1;
    for (int o = 32; o; o >>= 1) { s += __shfl_down(s, o); sq += __shfl_down(sq, o); }
    __shared__ float rs[4], rq[4], mb[2];
    int lane = t & 63, wv = t >> 6;
    if (!lane) { rs[wv] = s; rq[wv] = sq; }
    __syncthreads();
    if (t == 0) {
        float S = rs[0] + rs[1] + rs[2] + rs[3];
        float Q = rq[0] + rq[1] + rq[2] + rq[3];
        float mu = S * (1.f / DIMM);
        float var = Q * (1.f / DIMM) - mu * mu;
        mb[0] = mu; mb[1] = rsqrtf(var + 1e-5f);
    }
    __syncthreads();
    float mu = mb[0], invs = mb[1];
    y[(size_t)row * DIMM + t * 2]     = (__bf16)((v0 - mu) * invs * g[t * 2]     + bta[t * 2]);
    y[(size_t)row * DIMM + t * 2 + 1] = (__bf16)((v1 - mu) * invs * g[t * 2 + 1] + bta[t * 2 + 1]);
}

// ---------------- LDS-staged MFMA GEMM (m97 structure) ----------------
// C[M,N] = A[M,512] @ Wt[N,512]^T (+bias). 128x128 block tile, 4 waves x 64x64.
// BK=32, single LDS buffer, global_load_lds w16 staging with chunk^=(row>>1)&3
// swizzle applied on the GLOBAL source (LDS linear) and on ds_read (both sides).
template<int NCOLS, bool BIAS, bool OUT_F32>
__global__ __launch_bounds__(256) void gemm_lds(const __bf16* __restrict__ A,
                                                const __bf16* __restrict__ Wt,
                                                const float* __restrict__ bias,
                                                __bf16* __restrict__ outb,
                                                float* __restrict__ outf) {
    const int K = DIMM;
    __shared__ __align__(16) __bf16 As[128 * 32];
    __shared__ __align__(16) __bf16 Bs[128 * 32];

    const int tid = threadIdx.x;
    const int w = tid >> 6, lane = tid & 63;
    const int m = lane & 15, g = lane >> 4;
    const int mi = w >> 1, ni = w & 1;

    // staging: thread -> (row 0..63, chunk 0..3); source chunk pre-swizzled
    const int trow = tid >> 2;
    const int tc = tid & 3;
    const int sc = (tc ^ ((trow >> 1) & 3)) * 8;
    const __bf16* a0 = A  + (size_t)(blockIdx.x * 128 + trow) * K + sc;
    const __bf16* a1 = a0 + (size_t)64 * K;
    const __bf16* b0 = Wt + (size_t)(blockIdx.y * 128 + trow) * K + sc;
    const __bf16* b1 = b0 + (size_t)64 * K;
    char* lA0 = (char*)As + tid * 16;
    char* lA1 = (char*)As + 4096 + tid * 16;
    char* lB0 = (char*)Bs + tid * 16;
    char* lB1 = (char*)Bs + 4096 + tid * 16;

    f32x4 acc[4][4] = {};

    for (int k0 = 0; k0 < K; k0 += 32) {
        __syncthreads();                       // previous tile fully consumed
        GLOAD_LDS16(a0 + k0, lA0);
        GLOAD_LDS16(a1 + k0, lA1);
        GLOAD_LDS16(b0 + k0, lB0);
        GLOAD_LDS16(b1 + k0, lB1);
        __syncthreads();                       // vmcnt(0) drained -> tile visible

        bf16x8 af[4], bfr[4];
#pragma unroll
        for (int i = 0; i < 4; ++i) {
            const int ra = mi * 64 + i * 16 + m;
            af[i] = *reinterpret_cast<const bf16x8*>(
                (const char*)As + ra * 64 + ((g ^ ((ra >> 1) & 3)) << 4));
        }
#pragma unroll
        for (int j = 0; j < 4; ++j) {
            const int rb = ni * 64 + j * 16 + m;
            bfr[j] = *reinterpret_cast<const bf16x8*>(
                (const char*)Bs + rb * 64 + ((g ^ ((rb >> 1) & 3)) << 4));
        }
#pragma unroll
        for (int i = 0; i < 4; ++i)
#pragma unroll
            for (int j = 0; j < 4; ++j)
                acc[i][j] = __builtin_amdgcn_mfma_f32_16x16x32_bf16(af[i], bfr[j], acc[i][j], 0, 0, 0);
    }

    const int orow0 = blockIdx.x * 128 + mi * 64 + g * 4;
    const int ocol0 = blockIdx.y * 128 + ni * 64;
#pragma unroll
    for (int i = 0; i < 4; ++i)
#pragma unroll
        for (int j = 0; j < 4; ++j)
#pragma unroll
            for (int r = 0; r < 4; ++r) {
                int row = orow0 + i * 16 + r;
                int col = ocol0 + j * 16 + m;
                float v = acc[i][j][r];
                if (BIAS) v += bias[col];
                if (OUT_F32) outf[(size_t)row * NCOLS + col] = v;
                else         outb[(size_t)row * NCOLS + col] = (__bf16)v;
            }
}

// ---------------- MFMA flash attention (compiler-fenced, reg-staged) ----------------
// grid (8 q-blocks of 128 rows, 64 b*h); 512 threads = 8 waves, 16 q-rows/wave.
// S^T = mfma(K_frag, Q_frag)  -> lane owns q-row (lane&15): softmax lane-local + 2 shfl.
// P -> per-wave LDS (bf16) -> O^T = mfma(Vt_frag, P_frag): rescale + 1/l lane-local.
__global__ __launch_bounds__(512, 4) void attn_mfma(const __bf16* __restrict__ qkv,
                                                    __bf16* __restrict__ out) {
    const int qt = blockIdx.x, bh = blockIdx.y;
    const int b = bh >> 3, h = bh & 7;
    const int tid = threadIdx.x;
    const int w = tid >> 6, lane = tid & 63;
    const int g = lane >> 4, m = lane & 15;

    __shared__ __align__(16) __bf16 Kb[4096];      // [64 key][64 d], chunk c at c^(key&7)
    __shared__ __align__(16) __bf16 Vt[4096];      // [64 d][64 key], chunk c at c^((d>>3)^(d&7))
    __shared__ __align__(16) __bf16 Pl[8][1024];   // per-wave [16 q][64 key], chunk c at c^(q&7)

    bf16x8 qf[2];
    {
        const __bf16* qp = qkv + (size_t)(b * SEQ + qt * 128 + w * 16 + m) * TRIPLE + h * 64 + g * 8;
        qf[0] = *reinterpret_cast<const bf16x8*>(qp);
        qf[1] = *reinterpret_cast<const bf16x8*>(qp + 32);
#pragma unroll
        for (int e = 0; e < 8; ++e) {
            qf[0][e] = (__bf16)((float)qf[0][e] * 0.125f);
            qf[1][e] = (__bf16)((float)qf[1][e] * 0.125f);
        }
    }

    const int krow = tid >> 3;          // 0..63
    const int dc   = tid & 7;           // 0..7
    const size_t rbase = (size_t)(b * SEQ + krow) * TRIPLE + h * 64 + dc * 8;
    const __bf16* ksrc = qkv + rbase + DIMM;
    const __bf16* vsrc = qkv + rbase + 2 * DIMM;
    const int kstep = 64 * TRIPLE;

    char* kwp = (char*)Kb + krow * 128 + ((dc ^ (krow & 7)) << 4);
    char* vwp = (char*)Vt + dc * 1024 + (krow * 2);

    f32x4 oa[4] = {};
    float mrun = -1e30f, lrun = 0.f;

    uint4 kr_cur = *reinterpret_cast<const uint4*>(ksrc);
    uint4 vr_cur = *reinterpret_cast<const uint4*>(vsrc);
    uint4 kr_nxt = {}, vr_nxt = {};

    for (int t = 0; t < 16; ++t) {
        __syncthreads();

        *reinterpret_cast<bf16x8*>(kwp) = *reinterpret_cast<bf16x8*>(&kr_cur);
        {
            bf16x8 vv = *reinterpret_cast<bf16x8*>(&vr_cur);
#pragma unroll
            for (int e = 0; e < 8; ++e)
                *(__bf16*)(vwp + e * 128 + (((krow * 2) ^ (((dc ^ e) & 7) << 4)) - krow * 2)) = vv[e];
        }
        __syncthreads();

        if (t < 15) {
            kr_nxt = *reinterpret_cast<const uint4*>(ksrc + (size_t)(t + 1) * kstep);
            vr_nxt = *reinterpret_cast<const uint4*>(vsrc + (size_t)(t + 1) * kstep);
        }

        // ---- S^T = K @ Q^T ----
        const char* kb = (const char*)Kb;
        f32x4 sa[4];
#pragma unroll
        for (int i = 0; i < 4; ++i) sa[i] = (f32x4){0.f, 0.f, 0.f, 0.f};
#pragma unroll
        for (int kc = 0; kc < 2; ++kc) {
            const int cp = ((kc * 4 + g) ^ (m & 7)) << 4;
#pragma unroll
            for (int i = 0; i < 4; ++i) {
                bf16x8 kf = *reinterpret_cast<const bf16x8*>(kb + (i * 16 + m) * 128 + cp);
                sa[i] = __builtin_amdgcn_mfma_f32_16x16x32_bf16(kf, qf[kc], sa[i], 0, 0, 0);
            }
        }

        // ---- online softmax ----
        float mx = -1e30f;
#pragma unroll
        for (int i = 0; i < 4; ++i)
#pragma unroll
            for (int r = 0; r < 4; ++r) mx = fmaxf(mx, sa[i][r]);
        mx = fmaxf(mx, __shfl_xor(mx, 16));
        mx = fmaxf(mx, __shfl_xor(mx, 32));
        const float mnew = fmaxf(mrun, mx);
        float p[4][4];
        float ps = 0.f;
#pragma unroll
        for (int i = 0; i < 4; ++i)
#pragma unroll
            for (int r = 0; r < 4; ++r) { p[i][r] = __expf(sa[i][r] - mnew); ps += p[i][r]; }
        ps += __shfl_xor(ps, 16);
        ps += __shfl_xor(ps, 32);
        const float al = __expf(mrun - mnew);
        mrun = mnew;
        lrun = lrun * al + ps;
#pragma unroll
        for (int i = 0; i < 4; ++i)
#pragma unroll
            for (int r = 0; r < 4; ++r) oa[i][r] *= al;

        // ---- P -> per-wave LDS ----
        char* pw = (char*)Pl[w] + m * 128;
        const int psw = (m & 7) << 4;
#pragma unroll
        for (int i = 0; i < 4; ++i) {
            uint2 pk;
            asm("v_cvt_pk_bf16_f32 %0, %1, %2" : "=v"(pk.x) : "v"(p[i][0]), "v"(p[i][1]));
            asm("v_cvt_pk_bf16_f32 %0, %1, %2" : "=v"(pk.y) : "v"(p[i][2]), "v"(p[i][3]));
            *reinterpret_cast<uint2*>(pw + ((i * 32 + g * 8) ^ psw)) = pk;
        }

        // ---- O^T += V^T @ P^T ----
        bf16x8 pf[2];
#pragma unroll
        for (int kc = 0; kc < 2; ++kc)
            pf[kc] = *reinterpret_cast<const bf16x8*>(pw + ((kc * 64 + g * 16) ^ psw));
        const char* vb = (const char*)Vt;
#pragma unroll
        for (int kc = 0; kc < 2; ++kc)
#pragma unroll
            for (int i = 0; i < 4; ++i) {
                const int sv = ((i * 2 + (m >> 3)) ^ (m & 7)) & 7;
                bf16x8 vf = *reinterpret_cast<const bf16x8*>(
                    vb + (i * 16 + m) * 128 + (((kc * 4 + g) ^ sv) << 4));
                oa[i] = __builtin_amdgcn_mfma_f32_16x16x32_bf16(vf, pf[kc], oa[i], 0, 0, 0);
            }

        kr_cur = kr_nxt;
        vr_cur = vr_nxt;
    }

    const float inv = 1.0f / lrun;
    unsigned int* orow = (unsigned int*)(out + (size_t)(b * SEQ + qt * 128 + w * 16 + m) * DIMM + h * 64);
#pragma unroll
    for (int i = 0; i < 4; ++i)
#pragma unroll
        for (int rp = 0; rp < 2; ++rp) {
            float o0 = oa[i][2 * rp] * inv, o1 = oa[i][2 * rp + 1] * inv;
            unsigned int pk;
            asm("v_cvt_pk_bf16_f32 %0, %1, %2" : "=v"(pk) : "v"(o0), "v"(o1));
            orow[i * 8 + g * 2 + rp] = pk;
        }
}

// ---------------- launch ----------------
extern "C" void kernel_launch(void* const* d_in, const int* in_sizes, int n_in,
                              void* d_out, int out_size, void* d_ws, size_t ws_size,
                              hipStream_t stream) {
    const float* x     = (const float*)d_in[0];
    const float* g1    = (const float*)d_in[1];
    const float* b1    = (const float*)d_in[2];
    const float* W_qkv = (const float*)d_in[3];
    const float* g2    = (const float*)d_in[4];
    const float* b2    = (const float*)d_in[5];
    const float* W_out = (const float*)d_in[6];
    const float* b_out = (const float*)d_in[7];
    float* out = (float*)d_out;

    char* ws = (char*)d_ws;
    float* part1  = (float*)(ws);
    float* part2  = (float*)(ws + 1024);
    float* scales = (float*)(ws + 2048);
    __bf16* Wq1 = (__bf16*)(ws + 4096);                          // [1536,512]
    __bf16* Wq2 = (__bf16*)(ws + 4096 + 1572864);                // [512,512]
    __bf16* Xln = (__bf16*)(ws + 4096 + 1572864 + 524288);       // [8192,512] (reused for LN2 out)
    __bf16* QKV = (__bf16*)(ws + 4096 + 1572864 + 524288 + 8388608);            // [8192,1536]
    __bf16* AO  = (__bf16*)(ws + 4096 + 1572864 + 524288 + 8388608 + 25165824); // [8192,512]

    absum_partial<<<256, 256, 0, stream>>>(W_qkv, 786432, part1);
    absum_partial<<<256, 256, 0, stream>>>(W_out, 262144, part2);
    finalize_scales<<<1, 64, 0, stream>>>(part1, part2, scales);
    quant_ternary<<<768, 256, 0, stream>>>(W_qkv, 786432, scales, 0, Wq1);
    quant_ternary<<<256, 256, 0, stream>>>(W_out, 262144, scales, 1, Wq2);
    ln_rows<float><<<MROWS, 256, 0, stream>>>(x, g1, b1, Xln);
    gemm_lds<TRIPLE, false, false><<<dim3(64, 12), 256, 0, stream>>>(Xln, Wq1, nullptr, QKV, nullptr);
    attn_mfma<<<dim3(8, 64), 512, 0, stream>>>(QKV, AO);
    ln_rows<__bf16><<<MROWS, 256, 0, stream>>>(AO, g2, b2, Xln);
    gemm_lds<DIMM, true, true><<<dim3(64, 4), 256, 0, stream>>>(Xln, Wq2, b_out, nullptr, out);
}

// Round 5
// 103.692 us; speedup vs baseline: 6.1101x; 1.0774x over previous
//
#include <hip/hip_runtime.h>
#include <hip/hip_bf16.h>

typedef __bf16 bf16x8 __attribute__((ext_vector_type(8)));
typedef float  f32x4  __attribute__((ext_vector_type(4)));

#define SEQ   1024
#define BATCH 8
#define DIMM  512
#define HEADS 8
#define DHEAD 64
#define TRIPLE 1536
#define MROWS (BATCH*SEQ)   // 8192

#define GLOAD_LDS16(g, l) __builtin_amdgcn_global_load_lds( \
    (const __attribute__((address_space(1))) void*)(const void*)(g), \
    (__attribute__((address_space(3))) void*)(void*)(l), 16, 0, 0)

// ---------------- scale reduction (deterministic two-stage) ----------------
__global__ void absum_partial(const float* __restrict__ w, int n, float* __restrict__ part) {
    __shared__ float red[4];
    float s = 0.f;
    for (int i = blockIdx.x * blockDim.x + threadIdx.x; i < n; i += gridDim.x * blockDim.x)
        s += fabsf(w[i]);
    for (int o = 32; o; o >>= 1) s += __shfl_down(s, o);
    int lane = threadIdx.x & 63, wv = threadIdx.x >> 6;
    if (!lane) red[wv] = s;
    __syncthreads();
    if (threadIdx.x == 0) {
        float t = red[0] + red[1] + red[2] + red[3];
        part[blockIdx.x] = t;
    }
}

__global__ void finalize_scales(const float* __restrict__ p1, const float* __restrict__ p2,
                                float* __restrict__ scales) {
    int t = threadIdx.x;                 // 256 threads
    float v1 = p1[t], v2 = p2[t];
    for (int o = 32; o; o >>= 1) { v1 += __shfl_down(v1, o); v2 += __shfl_down(v2, o); }
    __shared__ float r1[4], r2[4];
    int lane = t & 63, wv = t >> 6;
    if (!lane) { r1[wv] = v1; r2[wv] = v2; }
    __syncthreads();
    if (t == 0) {
        scales[0] = (r1[0] + r1[1] + r1[2] + r1[3]) / 786432.0f;   // 1536*512
        scales[1] = (r2[0] + r2[1] + r2[2] + r2[3]) / 262144.0f;   // 512*512
    }
}

// ---------------- ternary quantize -> bf16 ----------------
__global__ void quant_ternary(const float* __restrict__ w, int n,
                              const float* __restrict__ scp, int si,
                              __bf16* __restrict__ out) {
    float s = scp[si];
    float inv = 1.f / (s + 1e-6f);
    int idx = (blockIdx.x * blockDim.x + threadIdx.x) * 4;
    if (idx + 3 < n) {
        float4 v = *reinterpret_cast<const float4*>(w + idx);
        out[idx + 0] = (__bf16)(rintf(fminf(1.f, fmaxf(-1.f, v.x * inv))) * s);
        out[idx + 1] = (__bf16)(rintf(fminf(1.f, fmaxf(-1.f, v.y * inv))) * s);
        out[idx + 2] = (__bf16)(rintf(fminf(1.f, fmaxf(-1.f, v.z * inv))) * s);
        out[idx + 3] = (__bf16)(rintf(fminf(1.f, fmaxf(-1.f, v.w * inv))) * s);
    }
}

// ---------------- layernorm (row = 512), output bf16 ----------------
template<typename TIN>
__global__ __launch_bounds__(256) void ln_rows(const TIN* __restrict__ x,
                                               const float* __restrict__ g,
                                               const float* __restrict__ bta,
                                               __bf16* __restrict__ y) {
    int row = blockIdx.x;
    int t = threadIdx.x;
    const TIN* xr = x + (size_t)row * DIMM;
    float v0 = (float)xr[t * 2], v1 = (float)xr[t * 2 + 1];
    float s = v0 + v1, sq = v0 * v0 + v1 * v1;
    for (int o = 32; o; o >>= 1) { s += __shfl_down(s, o); sq += __shfl_down(sq, o); }
    __shared__ float rs[4], rq[4], mb[2];
    int lane = t & 63, wv = t >> 6;
    if (!lane) { rs[wv] = s; rq[wv] = sq; }
    __syncthreads();
    if (t == 0) {
        float S = rs[0] + rs[1] + rs[2] + rs[3];
        float Q = rq[0] + rq[1] + rq[2] + rq[3];
        float mu = S * (1.f / DIMM);
        float var = Q * (1.f / DIMM) - mu * mu;
        mb[0] = mu; mb[1] = rsqrtf(var + 1e-5f);
    }
    __syncthreads();
    float mu = mb[0], invs = mb[1];
    y[(size_t)row * DIMM + t * 2]     = (__bf16)((v0 - mu) * invs * g[t * 2]     + bta[t * 2]);
    y[(size_t)row * DIMM + t * 2 + 1] = (__bf16)((v1 - mu) * invs * g[t * 2 + 1] + bta[t * 2 + 1]);
}

// ---------------- LDS-staged MFMA GEMM (m97 structure) ----------------
template<int NCOLS, bool BIAS, bool OUT_F32>
__global__ __launch_bounds__(256) void gemm_lds(const __bf16* __restrict__ A,
                                                const __bf16* __restrict__ Wt,
                                                const float* __restrict__ bias,
                                                __bf16* __restrict__ outb,
                                                float* __restrict__ outf) {
    const int K = DIMM;
    __shared__ __align__(16) __bf16 As[128 * 32];
    __shared__ __align__(16) __bf16 Bs[128 * 32];

    const int tid = threadIdx.x;
    const int w = tid >> 6, lane = tid & 63;
    const int m = lane & 15, g = lane >> 4;
    const int mi = w >> 1, ni = w & 1;

    const int trow = tid >> 2;
    const int tc = tid & 3;
    const int sc = (tc ^ ((trow >> 1) & 3)) * 8;
    const __bf16* a0 = A  + (size_t)(blockIdx.x * 128 + trow) * K + sc;
    const __bf16* a1 = a0 + (size_t)64 * K;
    const __bf16* b0 = Wt + (size_t)(blockIdx.y * 128 + trow) * K + sc;
    const __bf16* b1 = b0 + (size_t)64 * K;
    char* lA0 = (char*)As + tid * 16;
    char* lA1 = (char*)As + 4096 + tid * 16;
    char* lB0 = (char*)Bs + tid * 16;
    char* lB1 = (char*)Bs + 4096 + tid * 16;

    f32x4 acc[4][4] = {};

    for (int k0 = 0; k0 < K; k0 += 32) {
        __syncthreads();
        GLOAD_LDS16(a0 + k0, lA0);
        GLOAD_LDS16(a1 + k0, lA1);
        GLOAD_LDS16(b0 + k0, lB0);
        GLOAD_LDS16(b1 + k0, lB1);
        __syncthreads();

        bf16x8 af[4], bfr[4];
#pragma unroll
        for (int i = 0; i < 4; ++i) {
            const int ra = mi * 64 + i * 16 + m;
            af[i] = *reinterpret_cast<const bf16x8*>(
                (const char*)As + ra * 64 + ((g ^ ((ra >> 1) & 3)) << 4));
        }
#pragma unroll
        for (int j = 0; j < 4; ++j) {
            const int rb = ni * 64 + j * 16 + m;
            bfr[j] = *reinterpret_cast<const bf16x8*>(
                (const char*)Bs + rb * 64 + ((g ^ ((rb >> 1) & 3)) << 4));
        }
#pragma unroll
        for (int i = 0; i < 4; ++i)
#pragma unroll
            for (int j = 0; j < 4; ++j)
                acc[i][j] = __builtin_amdgcn_mfma_f32_16x16x32_bf16(af[i], bfr[j], acc[i][j], 0, 0, 0);
    }

    const int orow0 = blockIdx.x * 128 + mi * 64 + g * 4;
    const int ocol0 = blockIdx.y * 128 + ni * 64;
#pragma unroll
    for (int i = 0; i < 4; ++i)
#pragma unroll
        for (int j = 0; j < 4; ++j)
#pragma unroll
            for (int r = 0; r < 4; ++r) {
                int row = orow0 + i * 16 + r;
                int col = ocol0 + j * 16 + m;
                float v = acc[i][j][r];
                if (BIAS) v += bias[col];
                if (OUT_F32) outf[(size_t)row * NCOLS + col] = v;
                else         outb[(size_t)row * NCOLS + col] = (__bf16)v;
            }
}

// ---------------- MFMA flash attention, 32 q-rows/wave ----------------
// grid (8 q-blocks of 128 rows, 64 b*h); 256 threads = 4 waves, 32 q-rows/wave
// (two 16-row halves hf=0,1 sharing every K/V fragment read).
// S^T = mfma(K_frag, Q_frag): lane owns q-row (hf*16 + lane&15); softmax lane-local + 2 shfl.
// P -> per-wave LDS (bf16) -> O^T = mfma(Vt_frag, P_frag): rescale + 1/l lane-local.
__global__ __launch_bounds__(256, 2) void attn_mfma(const __bf16* __restrict__ qkv,
                                                    __bf16* __restrict__ out) {
    const int qt = blockIdx.x, bh = blockIdx.y;
    const int b = bh >> 3, h = bh & 7;
    const int tid = threadIdx.x;
    const int w = tid >> 6, lane = tid & 63;
    const int g = lane >> 4, m = lane & 15;

    __shared__ __align__(16) __bf16 Kb[4096];      // [64 key][64 d], chunk c at c^(key&7)
    __shared__ __align__(16) __bf16 Vt[4096];      // [64 d][64 key], chunk c at c^((d>>3)^(d&7))
    __shared__ __align__(16) __bf16 Pl[4][2048];   // per-wave [32 q][64 key], chunk c at c^(q&7)

    // Q fragments: qf[hf][kc] = Q[q = hf*16+m][d = kc*32 + g*8 + j], *0.125 (exact in bf16)
    bf16x8 qf[2][2];
    {
        const __bf16* qp = qkv + (size_t)(b * SEQ + qt * 128 + w * 32 + m) * TRIPLE + h * 64 + g * 8;
#pragma unroll
        for (int hf = 0; hf < 2; ++hf) {
            qf[hf][0] = *reinterpret_cast<const bf16x8*>(qp + (size_t)hf * 16 * TRIPLE);
            qf[hf][1] = *reinterpret_cast<const bf16x8*>(qp + (size_t)hf * 16 * TRIPLE + 32);
#pragma unroll
            for (int e = 0; e < 8; ++e) {
                qf[hf][0][e] = (__bf16)((float)qf[hf][0][e] * 0.125f);
                qf[hf][1][e] = (__bf16)((float)qf[hf][1][e] * 0.125f);
            }
        }
    }

    // staging: thread -> rows {srow, srow+32}, chunk sc
    const int srow = tid >> 3;          // 0..31
    const int sc   = tid & 7;           // 0..7
    const size_t rbase = (size_t)(b * SEQ + srow) * TRIPLE + h * 64 + sc * 8;
    const __bf16* k0s = qkv + rbase + DIMM;
    const __bf16* v0s = qkv + rbase + 2 * DIMM;
    const __bf16* k1s = k0s + (size_t)32 * TRIPLE;
    const __bf16* v1s = v0s + (size_t)32 * TRIPLE;
    const int kstep = 64 * TRIPLE;

    char* kw0 = (char*)Kb + srow * 128 + ((sc ^ (srow & 7)) << 4);
    char* kw1 = kw0 + 32 * 128;
    char* vbp = (char*)Vt;

    f32x4 oa[2][4] = {};
    float mrun[2] = {-1e30f, -1e30f}, lrun[2] = {0.f, 0.f};

    uint4 k0c = *reinterpret_cast<const uint4*>(k0s);
    uint4 k1c = *reinterpret_cast<const uint4*>(k1s);
    uint4 v0c = *reinterpret_cast<const uint4*>(v0s);
    uint4 v1c = *reinterpret_cast<const uint4*>(v1s);
    uint4 k0n = {}, k1n = {}, v0n = {}, v1n = {};

    for (int t = 0; t < 16; ++t) {
        __syncthreads();   // all waves done reading tile t-1

        *reinterpret_cast<bf16x8*>(kw0) = *reinterpret_cast<bf16x8*>(&k0c);
        *reinterpret_cast<bf16x8*>(kw1) = *reinterpret_cast<bf16x8*>(&k1c);
        {
            bf16x8 va = *reinterpret_cast<bf16x8*>(&v0c);
            bf16x8 vb = *reinterpret_cast<bf16x8*>(&v1c);
#pragma unroll
            for (int e = 0; e < 8; ++e) {
                const int dro = (sc * 8 + e) * 128;
                const int sw = ((sc ^ e) & 7) << 4;
                *(__bf16*)(vbp + dro + ((srow * 2) ^ sw))        = va[e];
                *(__bf16*)(vbp + dro + (((srow + 32) * 2) ^ sw)) = vb[e];
            }
        }
        __syncthreads();   // tile t visible

        if (t < 15) {      // next-tile loads overlap compute
            k0n = *reinterpret_cast<const uint4*>(k0s + (size_t)(t + 1) * kstep);
            k1n = *reinterpret_cast<const uint4*>(k1s + (size_t)(t + 1) * kstep);
            v0n = *reinterpret_cast<const uint4*>(v0s + (size_t)(t + 1) * kstep);
            v1n = *reinterpret_cast<const uint4*>(v1s + (size_t)(t + 1) * kstep);
        }

        // ---- S^T = K @ Q^T (K-frags shared by both q-halves) ----
        const char* kb = (const char*)Kb;
        f32x4 sa[2][4];
#pragma unroll
        for (int hf = 0; hf < 2; ++hf)
#pragma unroll
            for (int i = 0; i < 4; ++i) sa[hf][i] = (f32x4){0.f, 0.f, 0.f, 0.f};
#pragma unroll
        for (int kc = 0; kc < 2; ++kc) {
            const int cp = ((kc * 4 + g) ^ (m & 7)) << 4;
#pragma unroll
            for (int i = 0; i < 4; ++i) {
                bf16x8 kf = *reinterpret_cast<const bf16x8*>(kb + (i * 16 + m) * 128 + cp);
                sa[0][i] = __builtin_amdgcn_mfma_f32_16x16x32_bf16(kf, qf[0][kc], sa[0][i], 0, 0, 0);
                sa[1][i] = __builtin_amdgcn_mfma_f32_16x16x32_bf16(kf, qf[1][kc], sa[1][i], 0, 0, 0);
            }
        }

        // ---- online softmax per half + P pack/store ----
        char* pw = (char*)Pl[w] + m * 128;
        const int psw = (m & 7) << 4;
#pragma unroll
        for (int hf = 0; hf < 2; ++hf) {
            float mx = -1e30f;
#pragma unroll
            for (int i = 0; i < 4; ++i)
#pragma unroll
                for (int r = 0; r < 4; ++r) mx = fmaxf(mx, sa[hf][i][r]);
            mx = fmaxf(mx, __shfl_xor(mx, 16));
            mx = fmaxf(mx, __shfl_xor(mx, 32));
            const float mnew = fmaxf(mrun[hf], mx);
            float p[4][4];
            float ps = 0.f;
#pragma unroll
            for (int i = 0; i < 4; ++i)
#pragma unroll
                for (int r = 0; r < 4; ++r) { p[i][r] = __expf(sa[hf][i][r] - mnew); ps += p[i][r]; }
            ps += __shfl_xor(ps, 16);
            ps += __shfl_xor(ps, 32);
            const float al = __expf(mrun[hf] - mnew);
            mrun[hf] = mnew;
            lrun[hf] = lrun[hf] * al + ps;
#pragma unroll
            for (int i = 0; i < 4; ++i)
#pragma unroll
                for (int r = 0; r < 4; ++r) oa[hf][i][r] *= al;
#pragma unroll
            for (int i = 0; i < 4; ++i) {
                uint2 pk;
                asm("v_cvt_pk_bf16_f32 %0, %1, %2" : "=v"(pk.x) : "v"(p[i][0]), "v"(p[i][1]));
                asm("v_cvt_pk_bf16_f32 %0, %1, %2" : "=v"(pk.y) : "v"(p[i][2]), "v"(p[i][3]));
                *reinterpret_cast<uint2*>(pw + hf * 16 * 128 + ((i * 32 + g * 8) ^ psw)) = pk;
            }
        }

        // ---- P fragments ----
        bf16x8 pf[2][2];
#pragma unroll
        for (int hf = 0; hf < 2; ++hf)
#pragma unroll
            for (int kc = 0; kc < 2; ++kc)
                pf[hf][kc] = *reinterpret_cast<const bf16x8*>(
                    pw + hf * 16 * 128 + ((kc * 64 + g * 16) ^ psw));

        // ---- O^T += V^T @ P^T (V-frags shared by both halves) ----
#pragma unroll
        for (int kc = 0; kc < 2; ++kc)
#pragma unroll
            for (int i = 0; i < 4; ++i) {
                const int sv = ((i * 2 + (m >> 3)) ^ (m & 7)) & 7;
                bf16x8 vf = *reinterpret_cast<const bf16x8*>(
                    vbp + (i * 16 + m) * 128 + (((kc * 4 + g) ^ sv) << 4));
                oa[0][i] = __builtin_amdgcn_mfma_f32_16x16x32_bf16(vf, pf[0][kc], oa[0][i], 0, 0, 0);
                oa[1][i] = __builtin_amdgcn_mfma_f32_16x16x32_bf16(vf, pf[1][kc], oa[1][i], 0, 0, 0);
            }

        k0c = k0n; k1c = k1n; v0c = v0n; v1c = v1n;
    }

    // ---- epilogue ----
#pragma unroll
    for (int hf = 0; hf < 2; ++hf) {
        const float inv = 1.0f / lrun[hf];
        unsigned int* orow = (unsigned int*)(out +
            (size_t)(b * SEQ + qt * 128 + w * 32 + hf * 16 + m) * DIMM + h * 64);
#pragma unroll
        for (int i = 0; i < 4; ++i)
#pragma unroll
            for (int rp = 0; rp < 2; ++rp) {
                float o0 = oa[hf][i][2 * rp] * inv, o1 = oa[hf][i][2 * rp + 1] * inv;
                unsigned int pk;
                asm("v_cvt_pk_bf16_f32 %0, %1, %2" : "=v"(pk) : "v"(o0), "v"(o1));
                orow[i * 8 + g * 2 + rp] = pk;
            }
    }
}

// ---------------- launch ----------------
extern "C" void kernel_launch(void* const* d_in, const int* in_sizes, int n_in,
                              void* d_out, int out_size, void* d_ws, size_t ws_size,
                              hipStream_t stream) {
    const float* x     = (const float*)d_in[0];
    const float* g1    = (const float*)d_in[1];
    const float* b1    = (const float*)d_in[2];
    const float* W_qkv = (const float*)d_in[3];
    const float* g2    = (const float*)d_in[4];
    const float* b2    = (const float*)d_in[5];
    const float* W_out = (const float*)d_in[6];
    const float* b_out = (const float*)d_in[7];
    float* out = (float*)d_out;

    char* ws = (char*)d_ws;
    float* part1  = (float*)(ws);
    float* part2  = (float*)(ws + 1024);
    float* scales = (float*)(ws + 2048);
    __bf16* Wq1 = (__bf16*)(ws + 4096);                          // [1536,512]
    __bf16* Wq2 = (__bf16*)(ws + 4096 + 1572864);                // [512,512]
    __bf16* Xln = (__bf16*)(ws + 4096 + 1572864 + 524288);       // [8192,512] (reused for LN2 out)
    __bf16* QKV = (__bf16*)(ws + 4096 + 1572864 + 524288 + 8388608);            // [8192,1536]
    __bf16* AO  = (__bf16*)(ws + 4096 + 1572864 + 524288 + 8388608 + 25165824); // [8192,512]

    absum_partial<<<256, 256, 0, stream>>>(W_qkv, 786432, part1);
    absum_partial<<<256, 256, 0, stream>>>(W_out, 262144, part2);
    finalize_scales<<<1, 256, 0, stream>>>(part1, part2, scales);
    quant_ternary<<<768, 256, 0, stream>>>(W_qkv, 786432, scales, 0, Wq1);
    quant_ternary<<<256, 256, 0, stream>>>(W_out, 262144, scales, 1, Wq2);
    ln_rows<float><<<MROWS, 256, 0, stream>>>(x, g1, b1, Xln);
    gemm_lds<TRIPLE, false, false><<<dim3(64, 12), 256, 0, stream>>>(Xln, Wq1, nullptr, QKV, nullptr);
    attn_mfma<<<dim3(8, 64), 256, 0, stream>>>(QKV, AO);
    ln_rows<__bf16><<<MROWS, 256, 0, stream>>>(AO, g2, b2, Xln);
    gemm_lds<DIMM, true, true><<<dim3(64, 4), 256, 0, stream>>>(Xln, Wq2, b_out, nullptr, out);
}

// Round 6
// 90.397 us; speedup vs baseline: 7.0088x; 1.1471x over previous
//
#include <hip/hip_runtime.h>
#include <hip/hip_bf16.h>

typedef __bf16 bf16x8 __attribute__((ext_vector_type(8)));
typedef float  f32x4  __attribute__((ext_vector_type(4)));

#define SEQ   1024
#define BATCH 8
#define DIMM  512
#define HEADS 8
#define DHEAD 64
#define TRIPLE 1536
#define MROWS (BATCH*SEQ)   // 8192

#define GLOAD_LDS16(g, l) __builtin_amdgcn_global_load_lds( \
    (const __attribute__((address_space(1))) void*)(const void*)(g), \
    (__attribute__((address_space(3))) void*)(void*)(l), 16, 0, 0)

// ---------------- merged |w| partial sums ----------------
// blocks 0..255: W_qkv (786432 = 256*256*4*3); blocks 256..319: W_out (262144 = 64*256*4*4)
__global__ __launch_bounds__(256) void absum_all(const float* __restrict__ w1,
                                                 const float* __restrict__ w2,
                                                 float* __restrict__ part) {
    const int bid = blockIdx.x, tid = threadIdx.x;
    float s = 0.f;
    if (bid < 256) {
        const float4* p = (const float4*)w1;
        for (int i = bid * 256 + tid; i < 196608; i += 65536) {
            float4 v = p[i];
            s += fabsf(v.x) + fabsf(v.y) + fabsf(v.z) + fabsf(v.w);
        }
    } else {
        const float4* p = (const float4*)w2;
        for (int i = (bid - 256) * 256 + tid; i < 65536; i += 16384) {
            float4 v = p[i];
            s += fabsf(v.x) + fabsf(v.y) + fabsf(v.z) + fabsf(v.w);
        }
    }
    for (int o = 32; o; o >>= 1) s += __shfl_down(s, o);
    __shared__ float red[4];
    if (!(tid & 63)) red[tid >> 6] = s;
    __syncthreads();
    if (tid == 0) part[bid] = red[0] + red[1] + red[2] + red[3];
}

__global__ void finalize_scales(const float* __restrict__ part, float* __restrict__ scales) {
    int t = threadIdx.x;                 // 256 threads
    float v1 = part[t];
    float v2 = (t < 64) ? part[256 + t] : 0.f;
    for (int o = 32; o; o >>= 1) { v1 += __shfl_down(v1, o); v2 += __shfl_down(v2, o); }
    __shared__ float r1[4], r2[4];
    int lane = t & 63, wv = t >> 6;
    if (!lane) { r1[wv] = v1; r2[wv] = v2; }
    __syncthreads();
    if (t == 0) {
        scales[0] = (r1[0] + r1[1] + r1[2] + r1[3]) / 786432.0f;   // 1536*512
        scales[1] = (r2[0] + r2[1] + r2[2] + r2[3]) / 262144.0f;   // 512*512
    }
}

// ---------------- merged ternary quantize -> bf16 ----------------
// blocks 0..767: W_qkv; blocks 768..1023: W_out
__global__ __launch_bounds__(256) void quant_all(const float* __restrict__ w1,
                                                 const float* __restrict__ w2,
                                                 const float* __restrict__ scp,
                                                 __bf16* __restrict__ o1,
                                                 __bf16* __restrict__ o2) {
    const int bid = blockIdx.x;
    const float* w; __bf16* o; float s; int idx;
    if (bid < 768) { w = w1; o = o1; s = scp[0]; idx = (bid * 256 + threadIdx.x) * 4; }
    else           { w = w2; o = o2; s = scp[1]; idx = ((bid - 768) * 256 + threadIdx.x) * 4; }
    const float inv = 1.f / (s + 1e-6f);
    float4 v = *reinterpret_cast<const float4*>(w + idx);
    o[idx + 0] = (__bf16)(rintf(fminf(1.f, fmaxf(-1.f, v.x * inv))) * s);
    o[idx + 1] = (__bf16)(rintf(fminf(1.f, fmaxf(-1.f, v.y * inv))) * s);
    o[idx + 2] = (__bf16)(rintf(fminf(1.f, fmaxf(-1.f, v.z * inv))) * s);
    o[idx + 3] = (__bf16)(rintf(fminf(1.f, fmaxf(-1.f, v.w * inv))) * s);
}

// ---------------- wave-per-row layernorm (row = 512), output bf16 ----------------
// block = 256 threads = 4 waves = 4 rows; lane owns 8 elems; shfl-only reduction.
template<typename TIN>
__global__ __launch_bounds__(256) void ln_fast(const TIN* __restrict__ x,
                                               const float* __restrict__ g,
                                               const float* __restrict__ bta,
                                               __bf16* __restrict__ y) {
    const int row = blockIdx.x * 4 + (threadIdx.x >> 6);
    const int lane = threadIdx.x & 63;
    float v[8];
    if constexpr (sizeof(TIN) == 4) {
        const float4* xr = (const float4*)((const float*)x + (size_t)row * DIMM + lane * 8);
        float4 a = xr[0], bq = xr[1];
        v[0] = a.x; v[1] = a.y; v[2] = a.z; v[3] = a.w;
        v[4] = bq.x; v[5] = bq.y; v[6] = bq.z; v[7] = bq.w;
    } else {
        bf16x8 a = *reinterpret_cast<const bf16x8*>((const __bf16*)x + (size_t)row * DIMM + lane * 8);
#pragma unroll
        for (int e = 0; e < 8; ++e) v[e] = (float)a[e];
    }
    float s = 0.f, sq = 0.f;
#pragma unroll
    for (int e = 0; e < 8; ++e) { s += v[e]; sq += v[e] * v[e]; }
    for (int o = 32; o; o >>= 1) { s += __shfl_xor(s, o); sq += __shfl_xor(sq, o); }
    const float mu = s * (1.f / DIMM);
    const float invs = rsqrtf(sq * (1.f / DIMM) - mu * mu + 1e-5f);
    const float4* gp = (const float4*)(g + lane * 8);
    const float4* bp = (const float4*)(bta + lane * 8);
    float4 g0 = gp[0], g1 = gp[1], b0 = bp[0], b1 = bp[1];
    float o_[8] = {
        (v[0] - mu) * invs * g0.x + b0.x, (v[1] - mu) * invs * g0.y + b0.y,
        (v[2] - mu) * invs * g0.z + b0.z, (v[3] - mu) * invs * g0.w + b0.w,
        (v[4] - mu) * invs * g1.x + b1.x, (v[5] - mu) * invs * g1.y + b1.y,
        (v[6] - mu) * invs * g1.z + b1.z, (v[7] - mu) * invs * g1.w + b1.w };
    uint4 st;
    asm("v_cvt_pk_bf16_f32 %0, %1, %2" : "=v"(st.x) : "v"(o_[0]), "v"(o_[1]));
    asm("v_cvt_pk_bf16_f32 %0, %1, %2" : "=v"(st.y) : "v"(o_[2]), "v"(o_[3]));
    asm("v_cvt_pk_bf16_f32 %0, %1, %2" : "=v"(st.z) : "v"(o_[4]), "v"(o_[5]));
    asm("v_cvt_pk_bf16_f32 %0, %1, %2" : "=v"(st.w) : "v"(o_[6]), "v"(o_[7]));
    *reinterpret_cast<uint4*>(y + (size_t)row * DIMM + lane * 8) = st;
}

// ---------------- LDS-staged MFMA GEMM, single-barrier double-buffered ----------------
// C[M,N] = A[M,512] @ Wt[N,512]^T (+bias). 128x128 block tile, 4 waves x 64x64, BK=32.
// Per step: sync (drains tile-t loads) -> issue global_load_lds of t+1 into buf^1
// -> ds_read+MFMA on buf. Staging overlaps compute; one barrier per K-step.
template<int NCOLS, bool BIAS, bool OUT_F32>
__global__ __launch_bounds__(256) void gemm_lds(const __bf16* __restrict__ A,
                                                const __bf16* __restrict__ Wt,
                                                const float* __restrict__ bias,
                                                __bf16* __restrict__ outb,
                                                float* __restrict__ outf) {
    const int K = DIMM;
    __shared__ __align__(16) __bf16 As[2][4096];
    __shared__ __align__(16) __bf16 Bs[2][4096];

    const int tid = threadIdx.x;
    const int w = tid >> 6, lane = tid & 63;
    const int m = lane & 15, g = lane >> 4;
    const int mi = w >> 1, ni = w & 1;

    const int trow = tid >> 2;
    const int tc = tid & 3;
    const int sc = (tc ^ ((trow >> 1) & 3)) * 8;
    const __bf16* a0 = A  + (size_t)(blockIdx.x * 128 + trow) * K + sc;
    const __bf16* a1 = a0 + (size_t)64 * K;
    const __bf16* b0 = Wt + (size_t)(blockIdx.y * 128 + trow) * K + sc;
    const __bf16* b1 = b0 + (size_t)64 * K;

    f32x4 acc[4][4] = {};

    // prologue: tile 0 -> buf 0
    GLOAD_LDS16(a0, (char*)As[0] + tid * 16);
    GLOAD_LDS16(a1, (char*)As[0] + 4096 + tid * 16);
    GLOAD_LDS16(b0, (char*)Bs[0] + tid * 16);
    GLOAD_LDS16(b1, (char*)Bs[0] + 4096 + tid * 16);

    int cur = 0;
    for (int k0 = 0; k0 < K; k0 += 32) {
        __syncthreads();                       // vmcnt(0): tile k0 landed; buf^1 free
        if (k0 + 32 < K) {                     // stage tile k0+32 into buf^1 (overlaps MFMA)
            GLOAD_LDS16(a0 + k0 + 32, (char*)As[cur ^ 1] + tid * 16);
            GLOAD_LDS16(a1 + k0 + 32, (char*)As[cur ^ 1] + 4096 + tid * 16);
            GLOAD_LDS16(b0 + k0 + 32, (char*)Bs[cur ^ 1] + tid * 16);
            GLOAD_LDS16(b1 + k0 + 32, (char*)Bs[cur ^ 1] + 4096 + tid * 16);
        }

        const char* Ab = (const char*)As[cur];
        const char* Bb = (const char*)Bs[cur];
        bf16x8 af[4], bfr[4];
#pragma unroll
        for (int i = 0; i < 4; ++i) {
            const int ra = mi * 64 + i * 16 + m;
            af[i] = *reinterpret_cast<const bf16x8*>(Ab + ra * 64 + ((g ^ ((ra >> 1) & 3)) << 4));
        }
#pragma unroll
        for (int j = 0; j < 4; ++j) {
            const int rb = ni * 64 + j * 16 + m;
            bfr[j] = *reinterpret_cast<const bf16x8*>(Bb + rb * 64 + ((g ^ ((rb >> 1) & 3)) << 4));
        }
#pragma unroll
        for (int i = 0; i < 4; ++i)
#pragma unroll
            for (int j = 0; j < 4; ++j)
                acc[i][j] = __builtin_amdgcn_mfma_f32_16x16x32_bf16(af[i], bfr[j], acc[i][j], 0, 0, 0);
        cur ^= 1;
    }

    const int orow0 = blockIdx.x * 128 + mi * 64 + g * 4;
    const int ocol0 = blockIdx.y * 128 + ni * 64;
#pragma unroll
    for (int i = 0; i < 4; ++i)
#pragma unroll
        for (int j = 0; j < 4; ++j)
#pragma unroll
            for (int r = 0; r < 4; ++r) {
                int row = orow0 + i * 16 + r;
                int col = ocol0 + j * 16 + m;
                float v = acc[i][j][r];
                if (BIAS) v += bias[col];
                if (OUT_F32) outf[(size_t)row * NCOLS + col] = v;
                else         outb[(size_t)row * NCOLS + col] = (__bf16)v;
            }
}

// ---------------- MFMA flash attention, 32 q-rows/wave (unchanged, verified) ----------------
__global__ __launch_bounds__(256, 2) void attn_mfma(const __bf16* __restrict__ qkv,
                                                    __bf16* __restrict__ out) {
    const int qt = blockIdx.x, bh = blockIdx.y;
    const int b = bh >> 3, h = bh & 7;
    const int tid = threadIdx.x;
    const int w = tid >> 6, lane = tid & 63;
    const int g = lane >> 4, m = lane & 15;

    __shared__ __align__(16) __bf16 Kb[4096];      // [64 key][64 d], chunk c at c^(key&7)
    __shared__ __align__(16) __bf16 Vt[4096];      // [64 d][64 key], chunk c at c^((d>>3)^(d&7))
    __shared__ __align__(16) __bf16 Pl[4][2048];   // per-wave [32 q][64 key], chunk c at c^(q&7)

    bf16x8 qf[2][2];
    {
        const __bf16* qp = qkv + (size_t)(b * SEQ + qt * 128 + w * 32 + m) * TRIPLE + h * 64 + g * 8;
#pragma unroll
        for (int hf = 0; hf < 2; ++hf) {
            qf[hf][0] = *reinterpret_cast<const bf16x8*>(qp + (size_t)hf * 16 * TRIPLE);
            qf[hf][1] = *reinterpret_cast<const bf16x8*>(qp + (size_t)hf * 16 * TRIPLE + 32);
#pragma unroll
            for (int e = 0; e < 8; ++e) {
                qf[hf][0][e] = (__bf16)((float)qf[hf][0][e] * 0.125f);
                qf[hf][1][e] = (__bf16)((float)qf[hf][1][e] * 0.125f);
            }
        }
    }

    const int srow = tid >> 3;          // 0..31
    const int sc   = tid & 7;           // 0..7
    const size_t rbase = (size_t)(b * SEQ + srow) * TRIPLE + h * 64 + sc * 8;
    const __bf16* k0s = qkv + rbase + DIMM;
    const __bf16* v0s = qkv + rbase + 2 * DIMM;
    const __bf16* k1s = k0s + (size_t)32 * TRIPLE;
    const __bf16* v1s = v0s + (size_t)32 * TRIPLE;
    const int kstep = 64 * TRIPLE;

    char* kw0 = (char*)Kb + srow * 128 + ((sc ^ (srow & 7)) << 4);
    char* kw1 = kw0 + 32 * 128;
    char* vbp = (char*)Vt;

    f32x4 oa[2][4] = {};
    float mrun[2] = {-1e30f, -1e30f}, lrun[2] = {0.f, 0.f};

    uint4 k0c = *reinterpret_cast<const uint4*>(k0s);
    uint4 k1c = *reinterpret_cast<const uint4*>(k1s);
    uint4 v0c = *reinterpret_cast<const uint4*>(v0s);
    uint4 v1c = *reinterpret_cast<const uint4*>(v1s);
    uint4 k0n = {}, k1n = {}, v0n = {}, v1n = {};

    for (int t = 0; t < 16; ++t) {
        __syncthreads();

        *reinterpret_cast<bf16x8*>(kw0) = *reinterpret_cast<bf16x8*>(&k0c);
        *reinterpret_cast<bf16x8*>(kw1) = *reinterpret_cast<bf16x8*>(&k1c);
        {
            bf16x8 va = *reinterpret_cast<bf16x8*>(&v0c);
            bf16x8 vb = *reinterpret_cast<bf16x8*>(&v1c);
#pragma unroll
            for (int e = 0; e < 8; ++e) {
                const int dro = (sc * 8 + e) * 128;
                const int sw = ((sc ^ e) & 7) << 4;
                *(__bf16*)(vbp + dro + ((srow * 2) ^ sw))        = va[e];
                *(__bf16*)(vbp + dro + (((srow + 32) * 2) ^ sw)) = vb[e];
            }
        }
        __syncthreads();

        if (t < 15) {
            k0n = *reinterpret_cast<const uint4*>(k0s + (size_t)(t + 1) * kstep);
            k1n = *reinterpret_cast<const uint4*>(k1s + (size_t)(t + 1) * kstep);
            v0n = *reinterpret_cast<const uint4*>(v0s + (size_t)(t + 1) * kstep);
            v1n = *reinterpret_cast<const uint4*>(v1s + (size_t)(t + 1) * kstep);
        }

        // ---- S^T = K @ Q^T ----
        const char* kb = (const char*)Kb;
        f32x4 sa[2][4];
#pragma unroll
        for (int hf = 0; hf < 2; ++hf)
#pragma unroll
            for (int i = 0; i < 4; ++i) sa[hf][i] = (f32x4){0.f, 0.f, 0.f, 0.f};
#pragma unroll
        for (int kc = 0; kc < 2; ++kc) {
            const int cp = ((kc * 4 + g) ^ (m & 7)) << 4;
#pragma unroll
            for (int i = 0; i < 4; ++i) {
                bf16x8 kf = *reinterpret_cast<const bf16x8*>(kb + (i * 16 + m) * 128 + cp);
                sa[0][i] = __builtin_amdgcn_mfma_f32_16x16x32_bf16(kf, qf[0][kc], sa[0][i], 0, 0, 0);
                sa[1][i] = __builtin_amdgcn_mfma_f32_16x16x32_bf16(kf, qf[1][kc], sa[1][i], 0, 0, 0);
            }
        }

        // ---- online softmax per half + P pack/store ----
        char* pw = (char*)Pl[w] + m * 128;
        const int psw = (m & 7) << 4;
#pragma unroll
        for (int hf = 0; hf < 2; ++hf) {
            float mx = -1e30f;
#pragma unroll
            for (int i = 0; i < 4; ++i)
#pragma unroll
                for (int r = 0; r < 4; ++r) mx = fmaxf(mx, sa[hf][i][r]);
            mx = fmaxf(mx, __shfl_xor(mx, 16));
            mx = fmaxf(mx, __shfl_xor(mx, 32));
            const float mnew = fmaxf(mrun[hf], mx);
            float p[4][4];
            float ps = 0.f;
#pragma unroll
            for (int i = 0; i < 4; ++i)
#pragma unroll
                for (int r = 0; r < 4; ++r) { p[i][r] = __expf(sa[hf][i][r] - mnew); ps += p[i][r]; }
            ps += __shfl_xor(ps, 16);
            ps += __shfl_xor(ps, 32);
            const float al = __expf(mrun[hf] - mnew);
            mrun[hf] = mnew;
            lrun[hf] = lrun[hf] * al + ps;
#pragma unroll
            for (int i = 0; i < 4; ++i)
#pragma unroll
                for (int r = 0; r < 4; ++r) oa[hf][i][r] *= al;
#pragma unroll
            for (int i = 0; i < 4; ++i) {
                uint2 pk;
                asm("v_cvt_pk_bf16_f32 %0, %1, %2" : "=v"(pk.x) : "v"(p[i][0]), "v"(p[i][1]));
                asm("v_cvt_pk_bf16_f32 %0, %1, %2" : "=v"(pk.y) : "v"(p[i][2]), "v"(p[i][3]));
                *reinterpret_cast<uint2*>(pw + hf * 16 * 128 + ((i * 32 + g * 8) ^ psw)) = pk;
            }
        }

        // ---- P fragments ----
        bf16x8 pf[2][2];
#pragma unroll
        for (int hf = 0; hf < 2; ++hf)
#pragma unroll
            for (int kc = 0; kc < 2; ++kc)
                pf[hf][kc] = *reinterpret_cast<const bf16x8*>(
                    pw + hf * 16 * 128 + ((kc * 64 + g * 16) ^ psw));

        // ---- O^T += V^T @ P^T ----
#pragma unroll
        for (int kc = 0; kc < 2; ++kc)
#pragma unroll
            for (int i = 0; i < 4; ++i) {
                const int sv = ((i * 2 + (m >> 3)) ^ (m & 7)) & 7;
                bf16x8 vf = *reinterpret_cast<const bf16x8*>(
                    vbp + (i * 16 + m) * 128 + (((kc * 4 + g) ^ sv) << 4));
                oa[0][i] = __builtin_amdgcn_mfma_f32_16x16x32_bf16(vf, pf[0][kc], oa[0][i], 0, 0, 0);
                oa[1][i] = __builtin_amdgcn_mfma_f32_16x16x32_bf16(vf, pf[1][kc], oa[1][i], 0, 0, 0);
            }

        k0c = k0n; k1c = k1n; v0c = v0n; v1c = v1n;
    }

#pragma unroll
    for (int hf = 0; hf < 2; ++hf) {
        const float inv = 1.0f / lrun[hf];
        unsigned int* orow = (unsigned int*)(out +
            (size_t)(b * SEQ + qt * 128 + w * 32 + hf * 16 + m) * DIMM + h * 64);
#pragma unroll
        for (int i = 0; i < 4; ++i)
#pragma unroll
            for (int rp = 0; rp < 2; ++rp) {
                float o0 = oa[hf][i][2 * rp] * inv, o1 = oa[hf][i][2 * rp + 1] * inv;
                unsigned int pk;
                asm("v_cvt_pk_bf16_f32 %0, %1, %2" : "=v"(pk) : "v"(o0), "v"(o1));
                orow[i * 8 + g * 2 + rp] = pk;
            }
    }
}

// ---------------- launch ----------------
extern "C" void kernel_launch(void* const* d_in, const int* in_sizes, int n_in,
                              void* d_out, int out_size, void* d_ws, size_t ws_size,
                              hipStream_t stream) {
    const float* x     = (const float*)d_in[0];
    const float* g1    = (const float*)d_in[1];
    const float* b1    = (const float*)d_in[2];
    const float* W_qkv = (const float*)d_in[3];
    const float* g2    = (const float*)d_in[4];
    const float* b2    = (const float*)d_in[5];
    const float* W_out = (const float*)d_in[6];
    const float* b_out = (const float*)d_in[7];
    float* out = (float*)d_out;

    char* ws = (char*)d_ws;
    float* part   = (float*)(ws);                                // 320 floats
    float* scales = (float*)(ws + 2048);
    __bf16* Wq1 = (__bf16*)(ws + 4096);                          // [1536,512]
    __bf16* Wq2 = (__bf16*)(ws + 4096 + 1572864);                // [512,512]
    __bf16* Xln = (__bf16*)(ws + 4096 + 1572864 + 524288);       // [8192,512] (reused for LN2 out)
    __bf16* QKV = (__bf16*)(ws + 4096 + 1572864 + 524288 + 8388608);            // [8192,1536]
    __bf16* AO  = (__bf16*)(ws + 4096 + 1572864 + 524288 + 8388608 + 25165824); // [8192,512]

    absum_all<<<320, 256, 0, stream>>>(W_qkv, W_out, part);
    finalize_scales<<<1, 256, 0, stream>>>(part, scales);
    quant_all<<<1024, 256, 0, stream>>>(W_qkv, W_out, scales, Wq1, Wq2);
    ln_fast<float><<<MROWS / 4, 256, 0, stream>>>(x, g1, b1, Xln);
    gemm_lds<TRIPLE, false, false><<<dim3(64, 12), 256, 0, stream>>>(Xln, Wq1, nullptr, QKV, nullptr);
    attn_mfma<<<dim3(8, 64), 256, 0, stream>>>(QKV, AO);
    ln_fast<__bf16><<<MROWS / 4, 256, 0, stream>>>(AO, g2, b2, Xln);
    gemm_lds<DIMM, true, true><<<dim3(64, 4), 256, 0, stream>>>(Xln, Wq2, b_out, nullptr, out);
}